// Round 12
// baseline (182.566 us; speedup 1.0000x reference)
//
#include <hip/hip_runtime.h>
#include <stdint.h>

#define DIMD 512
#define BATCH 512
#define KSAMP 10
#define NCLS 8192
#define TREJ 32

typedef float f32x4 __attribute__((ext_vector_type(4)));
typedef long l2 __attribute__((ext_vector_type(2)));

// ---------------- RNG (counter-based, deterministic) ----------------
__device__ inline uint64_t sm64(uint64_t x) {
  x += 0x9E3779B97F4A7C15ull;
  x = (x ^ (x >> 30)) * 0xBF58476D1CE4E5B9ull;
  x = (x ^ (x >> 27)) * 0x94D049BB133111EBull;
  return x ^ (x >> 31);
}
__device__ inline float u01(uint32_t u) {
  return ((float)u + 0.5f) * 2.3283064365386963e-10f;
}
__device__ inline float normal_from(uint64_t r) {
  float u1 = u01((uint32_t)(r >> 32));
  float u2 = u01((uint32_t)r);
  return sqrtf(-2.0f * __logf(u1)) * __cosf(6.28318530718f * u2);
}
__device__ inline float gamma255(uint64_t& ctr) {
  const float dg = 255.1666667f;
  const float cg = 0.02086730f;
  for (int i = 0; i < 16; i++) {
    uint64_t r = sm64(ctr++);
    float x = normal_from(r);
    float t = fmaf(cg, x, 1.0f);
    if (t <= 0.0f) continue;
    float v3 = t * t * t;
    uint64_t r2 = sm64(ctr++);
    float u3 = u01((uint32_t)(r2 >> 32));
    if (__logf(u3) < 0.5f * x * x + dg * (1.0f - v3 + __logf(v3))) return dg * v3;
  }
  return dg;
}
__device__ inline float wave_sum(float v) {
  #pragma unroll
  for (int o = 32; o > 0; o >>= 1) v += __shfl_down(v, o, 64);
  return __shfl(v, 0, 64);
}
__device__ inline float vmf_logc(float k) {
  float k2 = k * k;
  float sm = sqrtf(65280.25f + k2);
  float sp = sqrtf(65792.25f + k2);
  return 127.75f * (__logf(255.5f + sm) + __logf(255.5f + sp)) - 0.5f * (sm + sp);
}
// pack 8 floats (scaled) -> 8 fp8 e4m3 bytes (2 dwords)
__device__ inline int2 pack_fp8x8(const float* v, float s) {
  int lo = 0, hi = 0;
  lo = __builtin_amdgcn_cvt_pk_fp8_f32(v[0] * s, v[1] * s, lo, false);
  lo = __builtin_amdgcn_cvt_pk_fp8_f32(v[2] * s, v[3] * s, lo, true);
  hi = __builtin_amdgcn_cvt_pk_fp8_f32(v[4] * s, v[5] * s, hi, false);
  hi = __builtin_amdgcn_cvt_pk_fp8_f32(v[6] * s, v[7] * s, hi, true);
  return make_int2(lo, hi);
}
// packed-row byte offset for lane l holding k in [8l, 8l+8) (verified map)
__device__ inline int pk_off(int l) {
  return ((l >> 3) << 6) + ((l & 3) << 4) + (((l & 7) < 4) ? 0 : 8);
}
// async global->LDS DMA, 16 B/lane. LDS dest = wave-uniform base + lane*16
// (hardware-defined); global src is per-lane (carries the kg swizzle).
__device__ inline void gld16(const unsigned char* g, unsigned char* l) {
  __builtin_amdgcn_global_load_lds(
      (const __attribute__((address_space(1))) unsigned int*)g,
      (__attribute__((address_space(3))) unsigned int*)l, 16, 0, 0);
}

// ---------- fused prep (blocks 0..2047, one WAVE per class) + sample ----------
__global__ __launch_bounds__(256) void prep_sample(const float* __restrict__ weight,
                                                   const float* __restrict__ params,
                                                   const float* __restrict__ lscale,
                                                   unsigned char* __restrict__ muW8,
                                                   float4* __restrict__ cparams,
                                                   float* __restrict__ rowsum,
                                                   float4* __restrict__ out4,
                                                   unsigned char* __restrict__ Sb8) {
  int blk = blockIdx.x, tid = threadIdx.x;
  int wave = tid >> 6, lane = tid & 63;
  if (blk < 2048) {
    out4[(size_t)blk * 512 + tid]       = make_float4(0.f, 0.f, 0.f, 0.f);
    out4[(size_t)blk * 512 + 256 + tid] = make_float4(0.f, 0.f, 0.f, 0.f);
    if (blk < 20) rowsum[blk * 256 + tid] = 0.0f;   // 20*256 = 5120

    int c = blk * 4 + wave;                 // one wave per class
    const float* wr = weight + (size_t)c * (DIMD + 2) + 1;
    float v[8];
    float n2 = 0.0f;
    #pragma unroll
    for (int j = 0; j < 8; j++) { v[j] = wr[lane * 8 + j]; n2 += v[j] * v[j]; }
    n2 = wave_sum(n2);
    float inv = rsqrtf(n2) * 16.0f;         // x16: dodge e4m3 subnormals
    int2 pk = pack_fp8x8(v, inv);
    *(int2*)(muW8 + (size_t)c * 512 + pk_off(lane)) = pk;

    float hik = wr[DIMD];                   // col 513
    float kw = __expf(-hik);
    float k1 = __expf(lscale[0]);
    float lcw = vmf_logc(kw);
    float A2 = fmaf(k1, k1, kw * kw);
    float B2 = 2.0f * k1 * kw;
    const float X0 = 0.9238795f, X1 = 0.3826834f;
    int l3 = lane & 3;
    float Xj = (l3 == 0) ? X0 : (l3 == 1) ? X1 : (l3 == 2) ? -X1 : -X0;
    float gj = lcw - vmf_logc(sqrtf(fmaf(B2, Xj, A2)));
    float g0 = __shfl(gj, 0, 64), g1 = __shfl(gj, 1, 64);
    float g2 = __shfl(gj, 2, 64), g3 = __shfl(gj, 3, 64);
    if (lane == 0) {
      float b0 = 0.25f * (g0 + g1 + g2 + g3);
      float b1 = 0.5f * (X0 * (g0 - g3) + X1 * (g1 - g2));
      float b2 = 0.5f * 0.7071068f * ((g0 + g3) - (g1 + g2));
      float b3 = 0.5f * (X1 * (g0 - g3) - X0 * (g1 - g2));
      const float L2E = 1.4426950409f;
      const float S1 = 1.0f / 256.0f;       // acc = 256*cos -> rescale poly
      cparams[c] = make_float4((b0 - b2) * L2E, (b1 - 3.0f * b3) * L2E * S1,
                               (2.0f * b2) * L2E * S1 * S1,
                               (4.0f * b3) * L2E * S1 * S1 * S1);
    }
  } else {
    // sample: 1 wave per row; lane l owns k in [8l, 8l+8) (contiguous).
    int row = (blk - 2048) * 4 + wave;      // b*KSAMP + k
    int b = row / KSAMP;
    const float* pr = params + (size_t)b * (DIMD + 2) + 1;

    float mu[8];
    float n2 = 0.0f;
    #pragma unroll
    for (int j = 0; j < 8; j++) { mu[j] = pr[lane * 8 + j]; n2 += mu[j] * mu[j]; }
    n2 = wave_sum(n2);
    float invn = rsqrtf(n2);
    #pragma unroll
    for (int j = 0; j < 8; j++) mu[j] *= invn;

    float kap = __expf(-pr[DIMD]);
    float bb = (-2.0f * kap + sqrtf(fmaf(4.0f * kap, kap, 511.0f * 511.0f))) / 511.0f;
    float x0 = (1.0f - bb) / (1.0f + bb);
    float cc = kap * x0 + 511.0f * __logf(1.0f - x0 * x0);

    uint64_t ctr = (((uint64_t)(row + 1)) << 32) | ((uint64_t)lane << 8);
    float g1 = gamma255(ctr);
    float g2 = gamma255(ctr);
    float z = g1 / (g1 + g2);
    float wt = (1.0f - (1.0f + bb) * z) / (1.0f - (1.0f - bb) * z);
    uint64_t r = sm64(ctr++);
    float u = u01((uint32_t)(r >> 32));
    float lhs = kap * wt + 511.0f * __logf(1.0f - x0 * wt) - cc;
    bool acc = (lane < TREJ) && (lhs >= __logf(fmaxf(u, 1e-10f)));
    uint64_t mask = __ballot(acc);
    int sel = mask ? (__ffsll((unsigned long long)mask) - 1) : 0;
    float w = __shfl(wt, sel, 64);

    uint64_t cbase = (((uint64_t)(row + 1)) << 32) | 0x40000000ull;
    float v[8];
    #pragma unroll
    for (int j = 0; j < 8; j++) v[j] = normal_from(sm64(cbase + (uint64_t)(lane * 8 + j)));
    float d = 0.0f;
    #pragma unroll
    for (int j = 0; j < 8; j++) d += v[j] * mu[j];
    d = wave_sum(d);
    float t2 = 0.0f;
    #pragma unroll
    for (int j = 0; j < 8; j++) { v[j] -= d * mu[j]; t2 += v[j] * v[j]; }
    t2 = wave_sum(t2);
    float ivt = rsqrtf(t2);
    float st = sqrtf(fmaxf(0.0f, 1.0f - w * w)) * ivt;
    float sv[8];
    float s2 = 0.0f;
    #pragma unroll
    for (int j = 0; j < 8; j++) { sv[j] = fmaf(st, v[j], w * mu[j]); s2 += sv[j] * sv[j]; }
    s2 = wave_sum(s2);
    float is = rsqrtf(s2) * 16.0f;
    int2 pk = pack_fp8x8(sv, is);
    *(int2*)(Sb8 + (size_t)row * 512 + pk_off(lane)) = pk;
  }
}

// MFMA GEMM: fp8 e4m3 -- 8-phase 256^2/8-wave template (m201 quadrant).
// Resubmit of R11 (infra failure; logic audited: uniform barriers, always-
// satisfiable waits, in-bounds LDS/global, hazard-checked double-buffer).
// Hardening vs R11: explicit lgkmcnt(0)+sched_barrier(0) at phase entry
// (rule #18), builtin barriers throughout. Semantics unchanged.
//  geometry: BM=BN=256, BK=64; 512 thr = 8 waves (2M x 4N); wave tile
//   128x64 -> acc[8][4], 64 MFMA/K-tile/wave (4 quadrants x 16).
//  LDS: 2x16KB A + 2x16KB B = 64 KB. grid 640 (8-divisible XCD swizzle).
//  staging: verified kg-swizzle on per-lane global src + sA_ XOR read.
//  gates: tile t+1->buf1 issued P1/P2, vmcnt(0)+bar at P4 (pre-P5 reads);
//   tile t+2->buf0 issued P5/P6 (post-P3-exit-bar seal), gated at P8.
//  accumulation: K-tiles 0..7, .x then .y -- unchanged from passed rounds.
__global__ __launch_bounds__(512, 2) void gemm_lse(const unsigned char* __restrict__ Sb8,
                                                   const unsigned char* __restrict__ Wb8,
                                                   const float4* __restrict__ cparams,
                                                   float* __restrict__ rowsum) {
  __shared__ __align__(16) unsigned char As[2][256 * 64];   // 2 x 16 KB
  __shared__ __align__(16) unsigned char Bs[2][256 * 64];   // 2 x 16 KB
  int tid = threadIdx.x;
  int lane = tid & 63, wave = tid >> 6;    // wave 0..7
  int tx = lane & 15, tz = lane >> 4;
  int wm = wave >> 2, wn = wave & 3;       // 2M x 4N wave grid

  int id = blockIdx.x;                     // 640 = 8 XCD x (4 col x 20 row)
  int xcd = id & 7, lid = id >> 3;         // 80 blocks per XCD
  int c0 = (xcd * 4 + (lid & 3)) * 256;    // 4-coltile stripe per XCD
  int r0 = (lid >> 2) * 256;               // 20 row tiles

  int srow = lane >> 2;                    // 0..15 within chunk
  int slot = lane & 3;
  int kg = slot ^ ((srow >> 1) & 3);       // verified swizzle
  int sA_ = tz ^ ((tx >> 1) & 3);          // verified read-side XOR

  // global pointers: wave w stages chunks {2w, 2w+1} (16 rows each) of A and B
  const unsigned char* gA[2];
  const unsigned char* gB[2];
  #pragma unroll
  for (int c = 0; c < 2; c++) {
    gA[c] = Sb8 + (size_t)(r0 + (wave * 2 + c) * 16 + srow) * 512 + kg * 16;
    gB[c] = Wb8 + (size_t)(c0 + (wave * 2 + c) * 16 + srow) * 512 + kg * 16;
  }
  int ldsX0 = (wave * 2) * 1024;           // DMA adds lane*16

  f32x4 acc[8][4];
  #pragma unroll
  for (int i = 0; i < 8; i++)
    #pragma unroll
    for (int j = 0; j < 4; j++) acc[i][j] = (f32x4){0.f, 0.f, 0.f, 0.f};

#define STAGE_A(P, CI)                                        \
  { gld16(gA[0] + (CI) * 64, &As[P][ldsX0]);                  \
    gld16(gA[1] + (CI) * 64, &As[P][ldsX0 + 1024]); }
#define STAGE_B(P, CI)                                        \
  { gld16(gB[0] + (CI) * 64, &Bs[P][ldsX0]);                  \
    gld16(gB[1] + (CI) * 64, &Bs[P][ldsX0 + 1024]); }

#define RD_A(P, MI0, AF)                                                   \
  _Pragma("unroll")                                                        \
  for (int mi = 0; mi < 4; mi++)                                           \
    AF[mi] = *(const l2*)&As[P][(wm * 128 + ((MI0) + mi) * 16 + tx) * 64 + sA_ * 16];
#define RD_B(P, BF)                                                        \
  _Pragma("unroll")                                                        \
  for (int ni = 0; ni < 4; ni++)                                           \
    BF[ni] = *(const l2*)&Bs[P][(wn * 64 + ni * 16 + tx) * 64 + sA_ * 16];

#define MF16(AF, BF, MIB, COMP)                                            \
  _Pragma("unroll")                                                        \
  for (int mi = 0; mi < 4; mi++)                                           \
    _Pragma("unroll")                                                      \
    for (int ni = 0; ni < 4; ni++)                                         \
      acc[(MIB) + mi][ni] = __builtin_amdgcn_mfma_f32_16x16x32_fp8_fp8(    \
          AF[mi].COMP, BF[ni].COMP, acc[(MIB) + mi][ni], 0, 0, 0);

// phase entry: barrier; drain ds_reads; pin order; boost prio (T3+T5).
#define PH_IN                                                              \
  __builtin_amdgcn_s_barrier();                                            \
  asm volatile("s_waitcnt lgkmcnt(0)" ::: "memory");                       \
  __builtin_amdgcn_sched_barrier(0);                                       \
  __builtin_amdgcn_s_setprio(1);
#define PH_OUT                                                             \
  __builtin_amdgcn_s_setprio(0);                                           \
  __builtin_amdgcn_sched_barrier(0);                                       \
  __builtin_amdgcn_s_barrier();
#define VM0 asm volatile("s_waitcnt vmcnt(0)" ::: "memory")

  // 8 phases per iteration = 2 K-tiles (t -> buf0, t+1 -> buf1).
#define GITER(T)                                                           \
  { l2 a03[4], a47[4], bf[4];                                              \
    /* P1: read buf0 Q1 operands; issue A-stage of t+1 into buf1 */        \
    RD_A(0, 0, a03) RD_B(0, bf)                                            \
    if ((T) + 1 < 8) STAGE_A(1, (T) + 1);                                  \
    PH_IN MF16(a03, bf, 0, x) PH_OUT                                       \
    /* P2: issue B-stage of t+1 */                                         \
    if ((T) + 1 < 8) STAGE_B(1, (T) + 1);                                  \
    PH_IN MF16(a03, bf, 0, y) PH_OUT                                       \
    /* P3: read buf0 Q3 operands (last buf0 reads; exit bar seals them) */ \
    RD_A(0, 4, a47)                                                        \
    PH_IN MF16(a47, bf, 4, x) PH_OUT                                       \
    /* P4: gate -- my t+1 DMAs (issued P1/P2) drained; barrier => all */   \
    VM0;                                                                   \
    PH_IN MF16(a47, bf, 4, y) PH_OUT                                       \
    /* P5: read buf1 Q1 operands; issue A-stage of t+2 into buf0 */        \
    RD_A(1, 0, a03) RD_B(1, bf)                                            \
    if ((T) + 2 < 8) STAGE_A(0, (T) + 2);                                  \
    PH_IN MF16(a03, bf, 0, x) PH_OUT                                       \
    /* P6: issue B-stage of t+2 */                                         \
    if ((T) + 2 < 8) STAGE_B(0, (T) + 2);                                  \
    PH_IN MF16(a03, bf, 0, y) PH_OUT                                       \
    /* P7: read buf1 Q3 operands */                                        \
    RD_A(1, 4, a47)                                                        \
    PH_IN MF16(a47, bf, 4, x) PH_OUT                                       \
    /* P8: gate for next iter's buf0 (t+2) */                              \
    if ((T) + 2 < 8) VM0;                                                  \
    PH_IN MF16(a47, bf, 4, y) PH_OUT                                       \
  }

  // prologue: K-tile 0 -> buf0; drain; barrier (tile 1 staged inside iter 0)
  STAGE_A(0, 0) STAGE_B(0, 0)
  VM0;
  __builtin_amdgcn_s_barrier();

  GITER(0) GITER(2) GITER(4) GITER(6)

  // epilogue: s += 2^(cubic(acc)) per class (poly pre-scaled for acc=256*cos)
  float4 cp[4];
  #pragma unroll
  for (int ni = 0; ni < 4; ni++) cp[ni] = cparams[c0 + wn * 64 + ni * 16 + tx];

  #pragma unroll
  for (int mi = 0; mi < 8; mi++) {
    #pragma unroll
    for (int reg = 0; reg < 4; reg++) {
      float s = 0.0f;
      #pragma unroll
      for (int ni = 0; ni < 4; ni++) {
        float cv = acc[mi][ni][reg];
        float g = fmaf(fmaf(fmaf(cp[ni].w, cv, cp[ni].z), cv, cp[ni].y), cv, cp[ni].x);
        s += exp2f(g);
      }
      #pragma unroll
      for (int o = 1; o < 16; o <<= 1) s += __shfl_xor(s, o, 64);
      if (tx == 0)
        atomicAdd(&rowsum[r0 + wm * 128 + mi * 16 + tz * 4 + reg], s);
    }
  }
}

// finalize: recompute both unit vectors from raw fp32 inputs
__global__ __launch_bounds__(64) void finalize_kernel(const float* __restrict__ params,
                                                      const float* __restrict__ weight,
                                                      const float* __restrict__ rowsum,
                                                      const int* __restrict__ labels,
                                                      const float* __restrict__ lscale,
                                                      float* __restrict__ out) {
  int b = blockIdx.x;
  int lane = threadIdx.x;
  int lab = labels[b];
  const float* pr = params + (size_t)b * (DIMD + 2) + 1;
  const float* wr = weight + (size_t)lab * (DIMD + 2) + 1;
  float nx = 0.0f, nw = 0.0f, d = 0.0f;
  #pragma unroll
  for (int j = 0; j < 8; j++) {
    float xv = pr[j * 64 + lane];
    float wv = wr[j * 64 + lane];
    nx += xv * xv; nw += wv * wv; d += xv * wv;
  }
  nx = wave_sum(nx); nw = wave_sum(nw); d = wave_sum(d);
  if (lane == 0) {
    float k1 = expf(lscale[0]);
    float acc = 0.0f;
    #pragma unroll
    for (int k = 0; k < KSAMP; k++) acc += __logf(rowsum[b * KSAMP + k]);
    float loss = acc * (1.0f / KSAMP) - k1 * d * rsqrtf(nx) * rsqrtf(nw);
    out[(size_t)b * NCLS + lab] = -loss;
  }
}

// ---------------- launch ----------------
extern "C" void kernel_launch(void* const* d_in, const int* in_sizes, int n_in,
                              void* d_out, int out_size, void* d_ws, size_t ws_size,
                              hipStream_t stream) {
  const float* params = (const float*)d_in[0];
  const float* weight = (const float*)d_in[1];
  const float* lscale = (const float*)d_in[2];
  const int*   labels = (const int*)d_in[3];
  float* out = (float*)d_out;
  char* ws = (char*)d_ws;

  unsigned char* muW8    = (unsigned char*)(ws);                    // 8192*512 = 4,194,304
  unsigned char* Sb8     = (unsigned char*)(ws + 4194304);          // 5120*512 = 2,621,440
  float4*        cparams = (float4*)(ws + 6815744);                 // 8192*16  =   131,072
  float*         rowsum  = (float*)(ws + 6946816);                  // 5120*4   =    20,480

  hipLaunchKernelGGL(prep_sample, dim3(2048 + BATCH * KSAMP / 4), dim3(256), 0, stream,
                     weight, params, lscale, muW8, cparams, rowsum, (float4*)out, Sb8);
  hipLaunchKernelGGL(gemm_lse, dim3((NCLS / 256) * (BATCH * KSAMP / 256)), dim3(512), 0, stream,
                     Sb8, muW8, cparams, rowsum);
  hipLaunchKernelGGL(finalize_kernel, dim3(BATCH), dim3(64), 0, stream,
                     params, weight, rowsum, labels, lscale, out);
}

// Round 13
// 179.466 us; speedup vs baseline: 1.0173x; 1.0173x over previous
//
#include <hip/hip_runtime.h>
#include <stdint.h>

#define DIMD 512
#define BATCH 512
#define KSAMP 10
#define NCLS 8192
#define TREJ 32

typedef float f32x4 __attribute__((ext_vector_type(4)));
typedef long l2 __attribute__((ext_vector_type(2)));

// ---------------- RNG (counter-based, deterministic) ----------------
__device__ inline uint64_t sm64(uint64_t x) {
  x += 0x9E3779B97F4A7C15ull;
  x = (x ^ (x >> 30)) * 0xBF58476D1CE4E5B9ull;
  x = (x ^ (x >> 27)) * 0x94D049BB133111EBull;
  return x ^ (x >> 31);
}
__device__ inline float u01(uint32_t u) {
  return ((float)u + 0.5f) * 2.3283064365386963e-10f;
}
__device__ inline float normal_from(uint64_t r) {
  float u1 = u01((uint32_t)(r >> 32));
  float u2 = u01((uint32_t)r);
  return sqrtf(-2.0f * __logf(u1)) * __cosf(6.28318530718f * u2);
}
__device__ inline float gamma255(uint64_t& ctr) {
  const float dg = 255.1666667f;
  const float cg = 0.02086730f;
  for (int i = 0; i < 16; i++) {
    uint64_t r = sm64(ctr++);
    float x = normal_from(r);
    float t = fmaf(cg, x, 1.0f);
    if (t <= 0.0f) continue;
    float v3 = t * t * t;
    uint64_t r2 = sm64(ctr++);
    float u3 = u01((uint32_t)(r2 >> 32));
    if (__logf(u3) < 0.5f * x * x + dg * (1.0f - v3 + __logf(v3))) return dg * v3;
  }
  return dg;
}
__device__ inline float wave_sum(float v) {
  #pragma unroll
  for (int o = 32; o > 0; o >>= 1) v += __shfl_down(v, o, 64);
  return __shfl(v, 0, 64);
}
__device__ inline float vmf_logc(float k) {
  float k2 = k * k;
  float sm = sqrtf(65280.25f + k2);
  float sp = sqrtf(65792.25f + k2);
  return 127.75f * (__logf(255.5f + sm) + __logf(255.5f + sp)) - 0.5f * (sm + sp);
}
// pack 8 floats (scaled) -> 8 fp8 e4m3 bytes (2 dwords)
__device__ inline int2 pack_fp8x8(const float* v, float s) {
  int lo = 0, hi = 0;
  lo = __builtin_amdgcn_cvt_pk_fp8_f32(v[0] * s, v[1] * s, lo, false);
  lo = __builtin_amdgcn_cvt_pk_fp8_f32(v[2] * s, v[3] * s, lo, true);
  hi = __builtin_amdgcn_cvt_pk_fp8_f32(v[4] * s, v[5] * s, hi, false);
  hi = __builtin_amdgcn_cvt_pk_fp8_f32(v[6] * s, v[7] * s, hi, true);
  return make_int2(lo, hi);
}
// packed-row byte offset for lane l holding k in [8l, 8l+8) (verified map)
__device__ inline int pk_off(int l) {
  return ((l >> 3) << 6) + ((l & 3) << 4) + (((l & 7) < 4) ? 0 : 8);
}
// async global->LDS DMA, 16 B/lane. LDS dest = wave-uniform base + lane*16
// (hardware-defined); global src is per-lane (carries the kg swizzle).
__device__ inline void gld16(const unsigned char* g, unsigned char* l) {
  __builtin_amdgcn_global_load_lds(
      (const __attribute__((address_space(1))) unsigned int*)g,
      (__attribute__((address_space(3))) unsigned int*)l, 16, 0, 0);
}

// ---------- fused prep (blocks 0..2047, one WAVE per class) + sample ----------
__global__ __launch_bounds__(256) void prep_sample(const float* __restrict__ weight,
                                                   const float* __restrict__ params,
                                                   const float* __restrict__ lscale,
                                                   unsigned char* __restrict__ muW8,
                                                   float4* __restrict__ cparams,
                                                   float* __restrict__ rowsum,
                                                   float4* __restrict__ out4,
                                                   unsigned char* __restrict__ Sb8) {
  int blk = blockIdx.x, tid = threadIdx.x;
  int wave = tid >> 6, lane = tid & 63;
  if (blk < 2048) {
    out4[(size_t)blk * 512 + tid]       = make_float4(0.f, 0.f, 0.f, 0.f);
    out4[(size_t)blk * 512 + 256 + tid] = make_float4(0.f, 0.f, 0.f, 0.f);
    if (blk < 20) rowsum[blk * 256 + tid] = 0.0f;   // 20*256 = 5120

    int c = blk * 4 + wave;                 // one wave per class
    const float* wr = weight + (size_t)c * (DIMD + 2) + 1;
    float v[8];
    float n2 = 0.0f;
    #pragma unroll
    for (int j = 0; j < 8; j++) { v[j] = wr[lane * 8 + j]; n2 += v[j] * v[j]; }
    n2 = wave_sum(n2);
    float inv = rsqrtf(n2) * 16.0f;         // x16: dodge e4m3 subnormals
    int2 pk = pack_fp8x8(v, inv);
    *(int2*)(muW8 + (size_t)c * 512 + pk_off(lane)) = pk;

    float hik = wr[DIMD];                   // col 513
    float kw = __expf(-hik);
    float k1 = __expf(lscale[0]);
    float lcw = vmf_logc(kw);
    float A2 = fmaf(k1, k1, kw * kw);
    float B2 = 2.0f * k1 * kw;
    const float X0 = 0.9238795f, X1 = 0.3826834f;
    int l3 = lane & 3;
    float Xj = (l3 == 0) ? X0 : (l3 == 1) ? X1 : (l3 == 2) ? -X1 : -X0;
    float gj = lcw - vmf_logc(sqrtf(fmaf(B2, Xj, A2)));
    float g0 = __shfl(gj, 0, 64), g1 = __shfl(gj, 1, 64);
    float g2 = __shfl(gj, 2, 64), g3 = __shfl(gj, 3, 64);
    if (lane == 0) {
      float b0 = 0.25f * (g0 + g1 + g2 + g3);
      float b1 = 0.5f * (X0 * (g0 - g3) + X1 * (g1 - g2));
      float b2 = 0.5f * 0.7071068f * ((g0 + g3) - (g1 + g2));
      float b3 = 0.5f * (X1 * (g0 - g3) - X0 * (g1 - g2));
      const float L2E = 1.4426950409f;
      const float S1 = 1.0f / 256.0f;       // acc = 256*cos -> rescale poly
      cparams[c] = make_float4((b0 - b2) * L2E, (b1 - 3.0f * b3) * L2E * S1,
                               (2.0f * b2) * L2E * S1 * S1,
                               (4.0f * b3) * L2E * S1 * S1 * S1);
    }
  } else {
    // sample: 1 wave per row; lane l owns k in [8l, 8l+8) (contiguous).
    int row = (blk - 2048) * 4 + wave;      // b*KSAMP + k
    int b = row / KSAMP;
    const float* pr = params + (size_t)b * (DIMD + 2) + 1;

    float mu[8];
    float n2 = 0.0f;
    #pragma unroll
    for (int j = 0; j < 8; j++) { mu[j] = pr[lane * 8 + j]; n2 += mu[j] * mu[j]; }
    n2 = wave_sum(n2);
    float invn = rsqrtf(n2);
    #pragma unroll
    for (int j = 0; j < 8; j++) mu[j] *= invn;

    float kap = __expf(-pr[DIMD]);
    float bb = (-2.0f * kap + sqrtf(fmaf(4.0f * kap, kap, 511.0f * 511.0f))) / 511.0f;
    float x0 = (1.0f - bb) / (1.0f + bb);
    float cc = kap * x0 + 511.0f * __logf(1.0f - x0 * x0);

    uint64_t ctr = (((uint64_t)(row + 1)) << 32) | ((uint64_t)lane << 8);
    float g1 = gamma255(ctr);
    float g2 = gamma255(ctr);
    float z = g1 / (g1 + g2);
    float wt = (1.0f - (1.0f + bb) * z) / (1.0f - (1.0f - bb) * z);
    uint64_t r = sm64(ctr++);
    float u = u01((uint32_t)(r >> 32));
    float lhs = kap * wt + 511.0f * __logf(1.0f - x0 * wt) - cc;
    bool acc = (lane < TREJ) && (lhs >= __logf(fmaxf(u, 1e-10f)));
    uint64_t mask = __ballot(acc);
    int sel = mask ? (__ffsll((unsigned long long)mask) - 1) : 0;
    float w = __shfl(wt, sel, 64);

    uint64_t cbase = (((uint64_t)(row + 1)) << 32) | 0x40000000ull;
    float v[8];
    #pragma unroll
    for (int j = 0; j < 8; j++) v[j] = normal_from(sm64(cbase + (uint64_t)(lane * 8 + j)));
    float d = 0.0f;
    #pragma unroll
    for (int j = 0; j < 8; j++) d += v[j] * mu[j];
    d = wave_sum(d);
    float t2 = 0.0f;
    #pragma unroll
    for (int j = 0; j < 8; j++) { v[j] -= d * mu[j]; t2 += v[j] * v[j]; }
    t2 = wave_sum(t2);
    float ivt = rsqrtf(t2);
    float st = sqrtf(fmaxf(0.0f, 1.0f - w * w)) * ivt;
    float sv[8];
    float s2 = 0.0f;
    #pragma unroll
    for (int j = 0; j < 8; j++) { sv[j] = fmaf(st, v[j], w * mu[j]); s2 += sv[j] * sv[j]; }
    s2 = wave_sum(s2);
    float is = rsqrtf(s2) * 16.0f;
    int2 pk = pack_fp8x8(sv, is);
    *(int2*)(Sb8 + (size_t)row * 512 + pk_off(lane)) = pk;
  }
}

// MFMA GEMM: fp8 e4m3 -- 8-phase 256^2/8-wave template, COUNTED gates (T4).
// R12 post-mortem: vmcnt(0) at P4/P8 waited on DMAs issued P1/P2 of the
// SAME iteration (~600cy old) -> full latency exposure 2x/iter; MfmaUtil 17%.
// Fix (m218 "counted-vs-drain0 = +38-73%"): re-time stage issue so gates
// can be counted --
//   P4: buf0 reads sealed by P3 exit barrier -> issue stage(t+2 -> buf0)
//       THEN vmcnt(4): retires t+1's 4 DMAs (a full K-tile old), t+2's 4
//       stay in flight. Barrier => all waves' t+1 stages visible.
//   P8: symmetric -- issue stage(t+3 -> buf1, sealed at P7), vmcnt(4)
//       retires t+2. Tail folds to vmcnt(0) on 8-phase-old DMAs (free).
// vmcnt FIFO-count semantics per m135. Geometry/read-path/accumulation
// order identical to R12 (which PASSED correctness) -> bitwise-same rowsum.
__global__ __launch_bounds__(512, 2) void gemm_lse(const unsigned char* __restrict__ Sb8,
                                                   const unsigned char* __restrict__ Wb8,
                                                   const float4* __restrict__ cparams,
                                                   float* __restrict__ rowsum) {
  __shared__ __align__(16) unsigned char As[2][256 * 64];   // 2 x 16 KB
  __shared__ __align__(16) unsigned char Bs[2][256 * 64];   // 2 x 16 KB
  int tid = threadIdx.x;
  int lane = tid & 63, wave = tid >> 6;    // wave 0..7
  int tx = lane & 15, tz = lane >> 4;
  int wm = wave >> 2, wn = wave & 3;       // 2M x 4N wave grid

  int id = blockIdx.x;                     // 640 = 8 XCD x (4 col x 20 row)
  int xcd = id & 7, lid = id >> 3;         // 80 blocks per XCD
  int c0 = (xcd * 4 + (lid & 3)) * 256;    // 4-coltile stripe per XCD
  int r0 = (lid >> 2) * 256;               // 20 row tiles

  int srow = lane >> 2;                    // 0..15 within chunk
  int slot = lane & 3;
  int kg = slot ^ ((srow >> 1) & 3);       // verified swizzle
  int sA_ = tz ^ ((tx >> 1) & 3);          // verified read-side XOR

  // global pointers: wave w stages chunks {2w, 2w+1} (16 rows each) of A and B
  const unsigned char* gA[2];
  const unsigned char* gB[2];
  #pragma unroll
  for (int c = 0; c < 2; c++) {
    gA[c] = Sb8 + (size_t)(r0 + (wave * 2 + c) * 16 + srow) * 512 + kg * 16;
    gB[c] = Wb8 + (size_t)(c0 + (wave * 2 + c) * 16 + srow) * 512 + kg * 16;
  }
  int ldsX0 = (wave * 2) * 1024;           // DMA adds lane*16

  f32x4 acc[8][4];
  #pragma unroll
  for (int i = 0; i < 8; i++)
    #pragma unroll
    for (int j = 0; j < 4; j++) acc[i][j] = (f32x4){0.f, 0.f, 0.f, 0.f};

#define STAGE_A(P, CI)                                        \
  { gld16(gA[0] + (CI) * 64, &As[P][ldsX0]);                  \
    gld16(gA[1] + (CI) * 64, &As[P][ldsX0 + 1024]); }
#define STAGE_B(P, CI)                                        \
  { gld16(gB[0] + (CI) * 64, &Bs[P][ldsX0]);                  \
    gld16(gB[1] + (CI) * 64, &Bs[P][ldsX0 + 1024]); }

#define RD_A(P, MI0, AF)                                                   \
  _Pragma("unroll")                                                        \
  for (int mi = 0; mi < 4; mi++)                                           \
    AF[mi] = *(const l2*)&As[P][(wm * 128 + ((MI0) + mi) * 16 + tx) * 64 + sA_ * 16];
#define RD_B(P, BF)                                                        \
  _Pragma("unroll")                                                        \
  for (int ni = 0; ni < 4; ni++)                                           \
    BF[ni] = *(const l2*)&Bs[P][(wn * 64 + ni * 16 + tx) * 64 + sA_ * 16];

#define MF16(AF, BF, MIB, COMP)                                            \
  _Pragma("unroll")                                                        \
  for (int mi = 0; mi < 4; mi++)                                           \
    _Pragma("unroll")                                                      \
    for (int ni = 0; ni < 4; ni++)                                         \
      acc[(MIB) + mi][ni] = __builtin_amdgcn_mfma_f32_16x16x32_fp8_fp8(    \
          AF[mi].COMP, BF[ni].COMP, acc[(MIB) + mi][ni], 0, 0, 0);

// phase entry: barrier; drain ds_reads; pin order; boost prio (T3+T5).
#define PH_IN                                                              \
  __builtin_amdgcn_s_barrier();                                            \
  asm volatile("s_waitcnt lgkmcnt(0)" ::: "memory");                       \
  __builtin_amdgcn_sched_barrier(0);                                       \
  __builtin_amdgcn_s_setprio(1);
#define PH_OUT                                                             \
  __builtin_amdgcn_s_setprio(0);                                           \
  __builtin_amdgcn_sched_barrier(0);                                       \
  __builtin_amdgcn_s_barrier();

// counted gate (T4): issue next stage into the just-sealed buffer, then
// vmcnt(4) = retire the PREVIOUS stage (1 K-tile old) while the new 4 fly.
// Tail: no stage left -> vmcnt(0) on DMAs issued >=4 phases ago (free).
#define GATE(P, CI)                                                        \
  if ((CI) < 8) {                                                          \
    STAGE_A(P, CI); STAGE_B(P, CI);                                        \
    asm volatile("s_waitcnt vmcnt(4)" ::: "memory");                       \
  } else {                                                                 \
    asm volatile("s_waitcnt vmcnt(0)" ::: "memory");                       \
  }

  // 8 phases per iteration = 2 K-tiles (t -> buf0, t+1 -> buf1).
#define GITER(T)                                                           \
  { l2 a03[4], a47[4], bf[4];                                              \
    /* P1: read buf0 Q1 operands */                                        \
    RD_A(0, 0, a03) RD_B(0, bf)                                            \
    PH_IN MF16(a03, bf, 0, x) PH_OUT                                       \
    /* P2 */                                                               \
    PH_IN MF16(a03, bf, 0, y) PH_OUT                                       \
    /* P3: read buf0 Q3 operands (LAST buf0 reads; exit bar seals) */      \
    RD_A(0, 4, a47)                                                        \
    PH_IN MF16(a47, bf, 4, x) PH_OUT                                       \
    /* P4: stage t+2 -> buf0 (sealed); counted gate retires t+1 */         \
    GATE(0, (T) + 2)                                                       \
    PH_IN MF16(a47, bf, 4, y) PH_OUT                                       \
    /* P5: read buf1 Q1 operands */                                        \
    RD_A(1, 0, a03) RD_B(1, bf)                                            \
    PH_IN MF16(a03, bf, 0, x) PH_OUT                                       \
    /* P6 */                                                               \
    PH_IN MF16(a03, bf, 0, y) PH_OUT                                       \
    /* P7: read buf1 Q3 operands (LAST buf1 reads; exit bar seals) */      \
    RD_A(1, 4, a47)                                                        \
    PH_IN MF16(a47, bf, 4, x) PH_OUT                                       \
    /* P8: stage t+3 -> buf1 (sealed); counted gate retires t+2 */         \
    GATE(1, (T) + 3)                                                       \
    PH_IN MF16(a47, bf, 4, y) PH_OUT                                       \
  }

  // prologue: tiles 0 -> buf0, 1 -> buf1 (8 DMAs); vmcnt(4) = tile 0
  // complete (tile 1's 4 in flight); barrier makes it block-wide.
  STAGE_A(0, 0) STAGE_B(0, 0)
  STAGE_A(1, 1) STAGE_B(1, 1)
  asm volatile("s_waitcnt vmcnt(4)" ::: "memory");
  __builtin_amdgcn_s_barrier();

  GITER(0) GITER(2) GITER(4) GITER(6)

  // epilogue: s += 2^(cubic(acc)) per class (poly pre-scaled for acc=256*cos)
  float4 cp[4];
  #pragma unroll
  for (int ni = 0; ni < 4; ni++) cp[ni] = cparams[c0 + wn * 64 + ni * 16 + tx];

  #pragma unroll
  for (int mi = 0; mi < 8; mi++) {
    #pragma unroll
    for (int reg = 0; reg < 4; reg++) {
      float s = 0.0f;
      #pragma unroll
      for (int ni = 0; ni < 4; ni++) {
        float cv = acc[mi][ni][reg];
        float g = fmaf(fmaf(fmaf(cp[ni].w, cv, cp[ni].z), cv, cp[ni].y), cv, cp[ni].x);
        s += exp2f(g);
      }
      #pragma unroll
      for (int o = 1; o < 16; o <<= 1) s += __shfl_xor(s, o, 64);
      if (tx == 0)
        atomicAdd(&rowsum[r0 + wm * 128 + mi * 16 + tz * 4 + reg], s);
    }
  }
}

// finalize: recompute both unit vectors from raw fp32 inputs
__global__ __launch_bounds__(64) void finalize_kernel(const float* __restrict__ params,
                                                      const float* __restrict__ weight,
                                                      const float* __restrict__ rowsum,
                                                      const int* __restrict__ labels,
                                                      const float* __restrict__ lscale,
                                                      float* __restrict__ out) {
  int b = blockIdx.x;
  int lane = threadIdx.x;
  int lab = labels[b];
  const float* pr = params + (size_t)b * (DIMD + 2) + 1;
  const float* wr = weight + (size_t)lab * (DIMD + 2) + 1;
  float nx = 0.0f, nw = 0.0f, d = 0.0f;
  #pragma unroll
  for (int j = 0; j < 8; j++) {
    float xv = pr[j * 64 + lane];
    float wv = wr[j * 64 + lane];
    nx += xv * xv; nw += wv * wv; d += xv * wv;
  }
  nx = wave_sum(nx); nw = wave_sum(nw); d = wave_sum(d);
  if (lane == 0) {
    float k1 = expf(lscale[0]);
    float acc = 0.0f;
    #pragma unroll
    for (int k = 0; k < KSAMP; k++) acc += __logf(rowsum[b * KSAMP + k]);
    float loss = acc * (1.0f / KSAMP) - k1 * d * rsqrtf(nx) * rsqrtf(nw);
    out[(size_t)b * NCLS + lab] = -loss;
  }
}

// ---------------- launch ----------------
extern "C" void kernel_launch(void* const* d_in, const int* in_sizes, int n_in,
                              void* d_out, int out_size, void* d_ws, size_t ws_size,
                              hipStream_t stream) {
  const float* params = (const float*)d_in[0];
  const float* weight = (const float*)d_in[1];
  const float* lscale = (const float*)d_in[2];
  const int*   labels = (const int*)d_in[3];
  float* out = (float*)d_out;
  char* ws = (char*)d_ws;

  unsigned char* muW8    = (unsigned char*)(ws);                    // 8192*512 = 4,194,304
  unsigned char* Sb8     = (unsigned char*)(ws + 4194304);          // 5120*512 = 2,621,440
  float4*        cparams = (float4*)(ws + 6815744);                 // 8192*16  =   131,072
  float*         rowsum  = (float*)(ws + 6946816);                  // 5120*4   =    20,480

  hipLaunchKernelGGL(prep_sample, dim3(2048 + BATCH * KSAMP / 4), dim3(256), 0, stream,
                     weight, params, lscale, muW8, cparams, rowsum, (float4*)out, Sb8);
  hipLaunchKernelGGL(gemm_lse, dim3((NCLS / 256) * (BATCH * KSAMP / 256)), dim3(512), 0, stream,
                     Sb8, muW8, cparams, rowsum);
  hipLaunchKernelGGL(finalize_kernel, dim3(BATCH), dim3(64), 0, stream,
                     params, weight, rowsum, labels, lscale, out);
}

// Round 14
// 138.336 us; speedup vs baseline: 1.3197x; 1.2973x over previous
//
#include <hip/hip_runtime.h>
#include <stdint.h>

#define DIMD 512
#define BATCH 512
#define KSAMP 10
#define NCLS 8192
#define TREJ 32

typedef float f32x4 __attribute__((ext_vector_type(4)));
typedef long l2 __attribute__((ext_vector_type(2)));

// ---------------- RNG (counter-based, deterministic) ----------------
__device__ inline uint64_t sm64(uint64_t x) {
  x += 0x9E3779B97F4A7C15ull;
  x = (x ^ (x >> 30)) * 0xBF58476D1CE4E5B9ull;
  x = (x ^ (x >> 27)) * 0x94D049BB133111EBull;
  return x ^ (x >> 31);
}
__device__ inline float u01(uint32_t u) {
  return ((float)u + 0.5f) * 2.3283064365386963e-10f;
}
__device__ inline float normal_from(uint64_t r) {
  float u1 = u01((uint32_t)(r >> 32));
  float u2 = u01((uint32_t)r);
  return sqrtf(-2.0f * __logf(u1)) * __cosf(6.28318530718f * u2);
}
__device__ inline float gamma255(uint64_t& ctr) {
  const float dg = 255.1666667f;
  const float cg = 0.02086730f;
  for (int i = 0; i < 16; i++) {
    uint64_t r = sm64(ctr++);
    float x = normal_from(r);
    float t = fmaf(cg, x, 1.0f);
    if (t <= 0.0f) continue;
    float v3 = t * t * t;
    uint64_t r2 = sm64(ctr++);
    float u3 = u01((uint32_t)(r2 >> 32));
    if (__logf(u3) < 0.5f * x * x + dg * (1.0f - v3 + __logf(v3))) return dg * v3;
  }
  return dg;
}
__device__ inline float wave_sum(float v) {
  #pragma unroll
  for (int o = 32; o > 0; o >>= 1) v += __shfl_down(v, o, 64);
  return __shfl(v, 0, 64);
}
__device__ inline float vmf_logc(float k) {
  float k2 = k * k;
  float sm = sqrtf(65280.25f + k2);
  float sp = sqrtf(65792.25f + k2);
  return 127.75f * (__logf(255.5f + sm) + __logf(255.5f + sp)) - 0.5f * (sm + sp);
}
// pack 8 floats (scaled) -> 8 fp8 e4m3 bytes (2 dwords)
__device__ inline int2 pack_fp8x8(const float* v, float s) {
  int lo = 0, hi = 0;
  lo = __builtin_amdgcn_cvt_pk_fp8_f32(v[0] * s, v[1] * s, lo, false);
  lo = __builtin_amdgcn_cvt_pk_fp8_f32(v[2] * s, v[3] * s, lo, true);
  hi = __builtin_amdgcn_cvt_pk_fp8_f32(v[4] * s, v[5] * s, hi, false);
  hi = __builtin_amdgcn_cvt_pk_fp8_f32(v[6] * s, v[7] * s, hi, true);
  return make_int2(lo, hi);
}
// packed-row byte offset for lane l holding k in [8l, 8l+8) (verified map)
__device__ inline int pk_off(int l) {
  return ((l >> 3) << 6) + ((l & 3) << 4) + (((l & 7) < 4) ? 0 : 8);
}
// async global->LDS DMA, 16 B/lane. LDS dest = wave-uniform base + lane*16
// (hardware-defined); global src is per-lane (carries the kg swizzle).
__device__ inline void gld16(const unsigned char* g, unsigned char* l) {
  __builtin_amdgcn_global_load_lds(
      (const __attribute__((address_space(1))) unsigned int*)g,
      (__attribute__((address_space(3))) unsigned int*)l, 16, 0, 0);
}

// ---------- fused prep (blocks 0..2047, one WAVE per class) + sample ----------
__global__ __launch_bounds__(256) void prep_sample(const float* __restrict__ weight,
                                                   const float* __restrict__ params,
                                                   const float* __restrict__ lscale,
                                                   unsigned char* __restrict__ muW8,
                                                   float4* __restrict__ cparams,
                                                   float* __restrict__ rowsum,
                                                   float4* __restrict__ out4,
                                                   unsigned char* __restrict__ Sb8) {
  int blk = blockIdx.x, tid = threadIdx.x;
  int wave = tid >> 6, lane = tid & 63;
  if (blk < 2048) {
    out4[(size_t)blk * 512 + tid]       = make_float4(0.f, 0.f, 0.f, 0.f);
    out4[(size_t)blk * 512 + 256 + tid] = make_float4(0.f, 0.f, 0.f, 0.f);
    if (blk < 20) rowsum[blk * 256 + tid] = 0.0f;   // 20*256 = 5120

    int c = blk * 4 + wave;                 // one wave per class
    const float* wr = weight + (size_t)c * (DIMD + 2) + 1;
    float v[8];
    float n2 = 0.0f;
    #pragma unroll
    for (int j = 0; j < 8; j++) { v[j] = wr[lane * 8 + j]; n2 += v[j] * v[j]; }
    n2 = wave_sum(n2);
    float inv = rsqrtf(n2) * 16.0f;         // x16: dodge e4m3 subnormals
    int2 pk = pack_fp8x8(v, inv);
    *(int2*)(muW8 + (size_t)c * 512 + pk_off(lane)) = pk;

    float hik = wr[DIMD];                   // col 513
    float kw = __expf(-hik);
    float k1 = __expf(lscale[0]);
    float lcw = vmf_logc(kw);
    float A2 = fmaf(k1, k1, kw * kw);
    float B2 = 2.0f * k1 * kw;
    const float X0 = 0.9238795f, X1 = 0.3826834f;
    int l3 = lane & 3;
    float Xj = (l3 == 0) ? X0 : (l3 == 1) ? X1 : (l3 == 2) ? -X1 : -X0;
    float gj = lcw - vmf_logc(sqrtf(fmaf(B2, Xj, A2)));
    float g0 = __shfl(gj, 0, 64), g1 = __shfl(gj, 1, 64);
    float g2 = __shfl(gj, 2, 64), g3 = __shfl(gj, 3, 64);
    if (lane == 0) {
      float b0 = 0.25f * (g0 + g1 + g2 + g3);
      float b1 = 0.5f * (X0 * (g0 - g3) + X1 * (g1 - g2));
      float b2 = 0.5f * 0.7071068f * ((g0 + g3) - (g1 + g2));
      float b3 = 0.5f * (X1 * (g0 - g3) - X0 * (g1 - g2));
      const float L2E = 1.4426950409f;
      const float S1 = 1.0f / 256.0f;       // acc = 256*cos -> rescale poly
      cparams[c] = make_float4((b0 - b2) * L2E, (b1 - 3.0f * b3) * L2E * S1,
                               (2.0f * b2) * L2E * S1 * S1,
                               (4.0f * b3) * L2E * S1 * S1 * S1);
    }
  } else {
    // sample: 1 wave per row; lane l owns k in [8l, 8l+8) (contiguous).
    int row = (blk - 2048) * 4 + wave;      // b*KSAMP + k
    int b = row / KSAMP;
    const float* pr = params + (size_t)b * (DIMD + 2) + 1;

    float mu[8];
    float n2 = 0.0f;
    #pragma unroll
    for (int j = 0; j < 8; j++) { mu[j] = pr[lane * 8 + j]; n2 += mu[j] * mu[j]; }
    n2 = wave_sum(n2);
    float invn = rsqrtf(n2);
    #pragma unroll
    for (int j = 0; j < 8; j++) mu[j] *= invn;

    float kap = __expf(-pr[DIMD]);
    float bb = (-2.0f * kap + sqrtf(fmaf(4.0f * kap, kap, 511.0f * 511.0f))) / 511.0f;
    float x0 = (1.0f - bb) / (1.0f + bb);
    float cc = kap * x0 + 511.0f * __logf(1.0f - x0 * x0);

    uint64_t ctr = (((uint64_t)(row + 1)) << 32) | ((uint64_t)lane << 8);
    float g1 = gamma255(ctr);
    float g2 = gamma255(ctr);
    float z = g1 / (g1 + g2);
    float wt = (1.0f - (1.0f + bb) * z) / (1.0f - (1.0f - bb) * z);
    uint64_t r = sm64(ctr++);
    float u = u01((uint32_t)(r >> 32));
    float lhs = kap * wt + 511.0f * __logf(1.0f - x0 * wt) - cc;
    bool acc = (lane < TREJ) && (lhs >= __logf(fmaxf(u, 1e-10f)));
    uint64_t mask = __ballot(acc);
    int sel = mask ? (__ffsll((unsigned long long)mask) - 1) : 0;
    float w = __shfl(wt, sel, 64);

    uint64_t cbase = (((uint64_t)(row + 1)) << 32) | 0x40000000ull;
    float v[8];
    #pragma unroll
    for (int j = 0; j < 8; j++) v[j] = normal_from(sm64(cbase + (uint64_t)(lane * 8 + j)));
    float d = 0.0f;
    #pragma unroll
    for (int j = 0; j < 8; j++) d += v[j] * mu[j];
    d = wave_sum(d);
    float t2 = 0.0f;
    #pragma unroll
    for (int j = 0; j < 8; j++) { v[j] -= d * mu[j]; t2 += v[j] * v[j]; }
    t2 = wave_sum(t2);
    float ivt = rsqrtf(t2);
    float st = sqrtf(fmaxf(0.0f, 1.0f - w * w)) * ivt;
    float sv[8];
    float s2 = 0.0f;
    #pragma unroll
    for (int j = 0; j < 8; j++) { sv[j] = fmaf(st, v[j], w * mu[j]); s2 += sv[j] * sv[j]; }
    s2 = wave_sum(s2);
    float is = rsqrtf(s2) * 16.0f;
    int2 pk = pack_fp8x8(sv, is);
    *(int2*)(Sb8 + (size_t)row * 512 + pk_off(lane)) = pk;
  }
}

// MFMA GEMM: fp8 e4m3, 256x128 tile, BK=64, 8 iterations, 4 waves, triple-
// buffered DMA staging. EXACT R7 configuration -- the best-measured kernel
// (gemm 52.7us, total 138.3us). The 8-phase template arc (R11-R13) is
// refuted at this problem shape: K=512 -> only 4 pipeline iterations, so
// the 16-barrier/iter schedule never amortizes (m201's wins assume deep K);
// R13 also showed a 20.9ms outlier dispatch (scheduling hazard risk).
// Plateau ledger: phases@4w (R3), occupancy x1.5/x2 (R2/R4), A-in-reg (R6),
// redundant-B (R8), merged-barrier (R9), memset-offload (R10), 8-phase
// drain0/counted (R12/R13) -- all refuted. This is the m97-class structural
// plateau (810 TF fp8 vs documented 874-912 ceiling for this structure).
__global__ __launch_bounds__(256, 2) void gemm_lse(const unsigned char* __restrict__ Sb8,
                                                   const unsigned char* __restrict__ Wb8,
                                                   const float4* __restrict__ cparams,
                                                   float* __restrict__ rowsum) {
  __shared__ __align__(16) unsigned char As[3][256 * 64];   // 3 x 16 KB
  __shared__ __align__(16) unsigned char Bs[3][128 * 64];   // 3 x 8 KB
  int tid = threadIdx.x;
  int lane = tid & 63, wave = tid >> 6;
  int tx = lane & 15, tz = lane >> 4;

  int id = blockIdx.x;                       // 64 col-tiles x 20 row-tiles = 1280
  int xcd = id & 7, lid = id >> 3;           // 160 blocks per XCD
  int c0 = (xcd * 8 + (lid & 7)) * 128;      // 8-coltile stripe per XCD
  int r0 = (lid >> 3) * 256;                 // sweep 20 row tiles

  int srow = lane >> 2;                      // 0..15 within chunk
  int slot = lane & 3;
  int kg = slot ^ ((srow >> 1) & 3);         // verified swizzle
  // global pointers: A chunks wave*4..+3 (16 rows each), B chunks wave*2..+1
  const unsigned char* gA[4];
  const unsigned char* gB[2];
  #pragma unroll
  for (int c = 0; c < 4; c++)
    gA[c] = Sb8 + (size_t)(r0 + (wave * 4 + c) * 16 + srow) * 512 + kg * 16;
  #pragma unroll
  for (int c = 0; c < 2; c++)
    gB[c] = Wb8 + (size_t)(c0 + (wave * 2 + c) * 16 + srow) * 512 + kg * 16;
  // wave-uniform LDS chunk bases (DMA adds lane*16)
  int ldsA0 = (wave * 4) * 1024;             // + c*1024
  int ldsB0 = (wave * 2) * 1024;

  f32x4 acc[4][8];
  #pragma unroll
  for (int i = 0; i < 4; i++)
    #pragma unroll
    for (int j = 0; j < 8; j++) acc[i][j] = (f32x4){0.f, 0.f, 0.f, 0.f};

#define STAGE(P, CI)                                         \
  { gld16(gA[0] + (CI) * 64, &As[P][ldsA0]);                 \
    gld16(gA[1] + (CI) * 64, &As[P][ldsA0 + 1024]);          \
    gld16(gA[2] + (CI) * 64, &As[P][ldsA0 + 2048]);          \
    gld16(gA[3] + (CI) * 64, &As[P][ldsA0 + 3072]);          \
    gld16(gB[0] + (CI) * 64, &Bs[P][ldsB0]);                 \
    gld16(gB[1] + (CI) * 64, &Bs[P][ldsB0 + 1024]); }

#define COMPUTE(P)                                                        \
  { l2 af[4];                                                             \
    int sA_ = tz ^ ((tx >> 1) & 3);                                       \
    _Pragma("unroll")                                                     \
    for (int mi = 0; mi < 4; mi++)                                        \
      af[mi] = *(const l2*)&As[P][(wave * 64 + mi * 16 + tx) * 64 + sA_ * 16]; \
    _Pragma("unroll")                                                     \
    for (int h = 0; h < 2; h++) {                                         \
      l2 bf[4];                                                           \
      _Pragma("unroll")                                                   \
      for (int ni = 0; ni < 4; ni++)                                      \
        bf[ni] = *(const l2*)&Bs[P][((h * 4 + ni) * 16 + tx) * 64 + sA_ * 16]; \
      _Pragma("unroll")                                                   \
      for (int mi = 0; mi < 4; mi++)                                      \
        _Pragma("unroll")                                                 \
        for (int ni = 0; ni < 4; ni++)                                    \
          acc[mi][h * 4 + ni] = __builtin_amdgcn_mfma_f32_16x16x32_fp8_fp8(af[mi].x, bf[ni].x, acc[mi][h * 4 + ni], 0, 0, 0); \
      _Pragma("unroll")                                                   \
      for (int mi = 0; mi < 4; mi++)                                      \
        _Pragma("unroll")                                                 \
        for (int ni = 0; ni < 4; ni++)                                    \
          acc[mi][h * 4 + ni] = __builtin_amdgcn_mfma_f32_16x16x32_fp8_fp8(af[mi].y, bf[ni].y, acc[mi][h * 4 + ni], 0, 0, 0); \
    } }

  // prologue: chunks 0,1,2 -> bufs 0,1,2 (18 DMAs); wait chunk 0
  // (12 newer outstanding); barrier.
  STAGE(0, 0);
  STAGE(1, 1);
  STAGE(2, 2);
  asm volatile("s_waitcnt vmcnt(12)" ::: "memory");
  __builtin_amdgcn_s_barrier();

  // iter t: compute buf (t%3); lgkm0+barrier (block done reading the buf);
  // stage chunk t+3 into the SAME buf; gate: chunk t+1 complete while
  // {t+2,t+3}'s DMAs (NGATE) stay in flight; barrier; next iter.
#define GITER(P, IT, NGATE)                                               \
  { COMPUTE(P);                                                           \
    if ((IT) < 7) {                                                       \
      asm volatile("s_waitcnt lgkmcnt(0)\n\ts_barrier" ::: "memory");     \
      if ((IT) + 3 < 8) STAGE(P, (IT) + 3);                               \
      asm volatile("s_waitcnt vmcnt(" #NGATE ")" ::: "memory");           \
      __builtin_amdgcn_s_barrier();                                       \
    } }

  GITER(0, 0, 12) GITER(1, 1, 12) GITER(2, 2, 12)
  GITER(0, 3, 12) GITER(1, 4, 12) GITER(2, 5, 6)
  GITER(0, 6, 0)  GITER(1, 7, 0)

  // epilogue: s += 2^(cubic(acc)) per class (poly pre-scaled for acc=256*cos)
  float4 cp[8];
  #pragma unroll
  for (int ni = 0; ni < 8; ni++) cp[ni] = cparams[c0 + ni * 16 + tx];

  #pragma unroll
  for (int mi = 0; mi < 4; mi++) {
    #pragma unroll
    for (int reg = 0; reg < 4; reg++) {
      float s = 0.0f;
      #pragma unroll
      for (int ni = 0; ni < 8; ni++) {
        float cv = acc[mi][ni][reg];
        float g = fmaf(fmaf(fmaf(cp[ni].w, cv, cp[ni].z), cv, cp[ni].y), cv, cp[ni].x);
        s += exp2f(g);
      }
      #pragma unroll
      for (int o = 1; o < 16; o <<= 1) s += __shfl_xor(s, o, 64);
      if (tx == 0)
        atomicAdd(&rowsum[r0 + wave * 64 + mi * 16 + tz * 4 + reg], s);
    }
  }
}

// finalize: recompute both unit vectors from raw fp32 inputs
__global__ __launch_bounds__(64) void finalize_kernel(const float* __restrict__ params,
                                                      const float* __restrict__ weight,
                                                      const float* __restrict__ rowsum,
                                                      const int* __restrict__ labels,
                                                      const float* __restrict__ lscale,
                                                      float* __restrict__ out) {
  int b = blockIdx.x;
  int lane = threadIdx.x;
  int lab = labels[b];
  const float* pr = params + (size_t)b * (DIMD + 2) + 1;
  const float* wr = weight + (size_t)lab * (DIMD + 2) + 1;
  float nx = 0.0f, nw = 0.0f, d = 0.0f;
  #pragma unroll
  for (int j = 0; j < 8; j++) {
    float xv = pr[j * 64 + lane];
    float wv = wr[j * 64 + lane];
    nx += xv * xv; nw += wv * wv; d += xv * wv;
  }
  nx = wave_sum(nx); nw = wave_sum(nw); d = wave_sum(d);
  if (lane == 0) {
    float k1 = expf(lscale[0]);
    float acc = 0.0f;
    #pragma unroll
    for (int k = 0; k < KSAMP; k++) acc += __logf(rowsum[b * KSAMP + k]);
    float loss = acc * (1.0f / KSAMP) - k1 * d * rsqrtf(nx) * rsqrtf(nw);
    out[(size_t)b * NCLS + lab] = -loss;
  }
}

// ---------------- launch ----------------
extern "C" void kernel_launch(void* const* d_in, const int* in_sizes, int n_in,
                              void* d_out, int out_size, void* d_ws, size_t ws_size,
                              hipStream_t stream) {
  const float* params = (const float*)d_in[0];
  const float* weight = (const float*)d_in[1];
  const float* lscale = (const float*)d_in[2];
  const int*   labels = (const int*)d_in[3];
  float* out = (float*)d_out;
  char* ws = (char*)d_ws;

  unsigned char* muW8    = (unsigned char*)(ws);                    // 8192*512 = 4,194,304
  unsigned char* Sb8     = (unsigned char*)(ws + 4194304);          // 5120*512 = 2,621,440
  float4*        cparams = (float4*)(ws + 6815744);                 // 8192*16  =   131,072
  float*         rowsum  = (float*)(ws + 6946816);                  // 5120*4   =    20,480

  hipLaunchKernelGGL(prep_sample, dim3(2048 + BATCH * KSAMP / 4), dim3(256), 0, stream,
                     weight, params, lscale, muW8, cparams, rowsum, (float4*)out, Sb8);
  hipLaunchKernelGGL(gemm_lse, dim3((NCLS / 128) * (BATCH * KSAMP / 256)), dim3(256), 0, stream,
                     Sb8, muW8, cparams, rowsum);
  hipLaunchKernelGGL(finalize_kernel, dim3(BATCH), dim3(64), 0, stream,
                     params, weight, rowsum, labels, lscale, out);
}

// Round 17
// 138.281 us; speedup vs baseline: 1.3203x; 1.0004x over previous
//
#include <hip/hip_runtime.h>
#include <stdint.h>

#define DIMD 512
#define BATCH 512
#define KSAMP 10
#define NCLS 8192
#define TREJ 32

typedef float f32x4 __attribute__((ext_vector_type(4)));
typedef long l2 __attribute__((ext_vector_type(2)));

// ---------------- RNG (counter-based, deterministic) ----------------
__device__ inline uint64_t sm64(uint64_t x) {
  x += 0x9E3779B97F4A7C15ull;
  x = (x ^ (x >> 30)) * 0xBF58476D1CE4E5B9ull;
  x = (x ^ (x >> 27)) * 0x94D049BB133111EBull;
  return x ^ (x >> 31);
}
__device__ inline float u01(uint32_t u) {
  return ((float)u + 0.5f) * 2.3283064365386963e-10f;
}
__device__ inline float normal_from(uint64_t r) {
  float u1 = u01((uint32_t)(r >> 32));
  float u2 = u01((uint32_t)r);
  return sqrtf(-2.0f * __logf(u1)) * __cosf(6.28318530718f * u2);
}
__device__ inline float gamma255(uint64_t& ctr) {
  const float dg = 255.1666667f;
  const float cg = 0.02086730f;
  for (int i = 0; i < 16; i++) {
    uint64_t r = sm64(ctr++);
    float x = normal_from(r);
    float t = fmaf(cg, x, 1.0f);
    if (t <= 0.0f) continue;
    float v3 = t * t * t;
    uint64_t r2 = sm64(ctr++);
    float u3 = u01((uint32_t)(r2 >> 32));
    if (__logf(u3) < 0.5f * x * x + dg * (1.0f - v3 + __logf(v3))) return dg * v3;
  }
  return dg;
}
__device__ inline float wave_sum(float v) {
  #pragma unroll
  for (int o = 32; o > 0; o >>= 1) v += __shfl_down(v, o, 64);
  return __shfl(v, 0, 64);
}
__device__ inline float vmf_logc(float k) {
  float k2 = k * k;
  float sm = sqrtf(65280.25f + k2);
  float sp = sqrtf(65792.25f + k2);
  return 127.75f * (__logf(255.5f + sm) + __logf(255.5f + sp)) - 0.5f * (sm + sp);
}
// pack 8 floats (scaled) -> 8 fp8 e4m3 bytes (2 dwords)
__device__ inline int2 pack_fp8x8(const float* v, float s) {
  int lo = 0, hi = 0;
  lo = __builtin_amdgcn_cvt_pk_fp8_f32(v[0] * s, v[1] * s, lo, false);
  lo = __builtin_amdgcn_cvt_pk_fp8_f32(v[2] * s, v[3] * s, lo, true);
  hi = __builtin_amdgcn_cvt_pk_fp8_f32(v[4] * s, v[5] * s, hi, false);
  hi = __builtin_amdgcn_cvt_pk_fp8_f32(v[6] * s, v[7] * s, hi, true);
  return make_int2(lo, hi);
}
// packed-row byte offset for lane l holding k in [8l, 8l+8) (verified map)
__device__ inline int pk_off(int l) {
  return ((l >> 3) << 6) + ((l & 3) << 4) + (((l & 7) < 4) ? 0 : 8);
}
// async global->LDS DMA, 16 B/lane. LDS dest = wave-uniform base + lane*16
// (hardware-defined); global src is per-lane (carries the kg swizzle).
__device__ inline void gld16(const unsigned char* g, unsigned char* l) {
  __builtin_amdgcn_global_load_lds(
      (const __attribute__((address_space(1))) unsigned int*)g,
      (__attribute__((address_space(3))) unsigned int*)l, 16, 0, 0);
}

// ---------- fused prep (blocks 0..2047, one WAVE per class) + sample ----------
// EXACT R14 configuration (best measured: total 138.3us, passed). The
// normal-approx sampler variant (R15/R16) container-failed twice -> reverted
// per the pre-committed fallback rule.
__global__ __launch_bounds__(256) void prep_sample(const float* __restrict__ weight,
                                                   const float* __restrict__ params,
                                                   const float* __restrict__ lscale,
                                                   unsigned char* __restrict__ muW8,
                                                   float4* __restrict__ cparams,
                                                   float* __restrict__ rowsum,
                                                   float4* __restrict__ out4,
                                                   unsigned char* __restrict__ Sb8) {
  int blk = blockIdx.x, tid = threadIdx.x;
  int wave = tid >> 6, lane = tid & 63;
  if (blk < 2048) {
    out4[(size_t)blk * 512 + tid]       = make_float4(0.f, 0.f, 0.f, 0.f);
    out4[(size_t)blk * 512 + 256 + tid] = make_float4(0.f, 0.f, 0.f, 0.f);
    if (blk < 20) rowsum[blk * 256 + tid] = 0.0f;   // 20*256 = 5120

    int c = blk * 4 + wave;                 // one wave per class
    const float* wr = weight + (size_t)c * (DIMD + 2) + 1;
    float v[8];
    float n2 = 0.0f;
    #pragma unroll
    for (int j = 0; j < 8; j++) { v[j] = wr[lane * 8 + j]; n2 += v[j] * v[j]; }
    n2 = wave_sum(n2);
    float inv = rsqrtf(n2) * 16.0f;         // x16: dodge e4m3 subnormals
    int2 pk = pack_fp8x8(v, inv);
    *(int2*)(muW8 + (size_t)c * 512 + pk_off(lane)) = pk;

    float hik = wr[DIMD];                   // col 513
    float kw = __expf(-hik);
    float k1 = __expf(lscale[0]);
    float lcw = vmf_logc(kw);
    float A2 = fmaf(k1, k1, kw * kw);
    float B2 = 2.0f * k1 * kw;
    const float X0 = 0.9238795f, X1 = 0.3826834f;
    int l3 = lane & 3;
    float Xj = (l3 == 0) ? X0 : (l3 == 1) ? X1 : (l3 == 2) ? -X1 : -X0;
    float gj = lcw - vmf_logc(sqrtf(fmaf(B2, Xj, A2)));
    float g0 = __shfl(gj, 0, 64), g1 = __shfl(gj, 1, 64);
    float g2 = __shfl(gj, 2, 64), g3 = __shfl(gj, 3, 64);
    if (lane == 0) {
      float b0 = 0.25f * (g0 + g1 + g2 + g3);
      float b1 = 0.5f * (X0 * (g0 - g3) + X1 * (g1 - g2));
      float b2 = 0.5f * 0.7071068f * ((g0 + g3) - (g1 + g2));
      float b3 = 0.5f * (X1 * (g0 - g3) - X0 * (g1 - g2));
      const float L2E = 1.4426950409f;
      const float S1 = 1.0f / 256.0f;       // acc = 256*cos -> rescale poly
      cparams[c] = make_float4((b0 - b2) * L2E, (b1 - 3.0f * b3) * L2E * S1,
                               (2.0f * b2) * L2E * S1 * S1,
                               (4.0f * b3) * L2E * S1 * S1 * S1);
    }
  } else {
    // sample: 1 wave per row; lane l owns k in [8l, 8l+8) (contiguous).
    int row = (blk - 2048) * 4 + wave;      // b*KSAMP + k
    int b = row / KSAMP;
    const float* pr = params + (size_t)b * (DIMD + 2) + 1;

    float mu[8];
    float n2 = 0.0f;
    #pragma unroll
    for (int j = 0; j < 8; j++) { mu[j] = pr[lane * 8 + j]; n2 += mu[j] * mu[j]; }
    n2 = wave_sum(n2);
    float invn = rsqrtf(n2);
    #pragma unroll
    for (int j = 0; j < 8; j++) mu[j] *= invn;

    float kap = __expf(-pr[DIMD]);
    float bb = (-2.0f * kap + sqrtf(fmaf(4.0f * kap, kap, 511.0f * 511.0f))) / 511.0f;
    float x0 = (1.0f - bb) / (1.0f + bb);
    float cc = kap * x0 + 511.0f * __logf(1.0f - x0 * x0);

    uint64_t ctr = (((uint64_t)(row + 1)) << 32) | ((uint64_t)lane << 8);
    float g1 = gamma255(ctr);
    float g2 = gamma255(ctr);
    float z = g1 / (g1 + g2);
    float wt = (1.0f - (1.0f + bb) * z) / (1.0f - (1.0f - bb) * z);
    uint64_t r = sm64(ctr++);
    float u = u01((uint32_t)(r >> 32));
    float lhs = kap * wt + 511.0f * __logf(1.0f - x0 * wt) - cc;
    bool acc = (lane < TREJ) && (lhs >= __logf(fmaxf(u, 1e-10f)));
    uint64_t mask = __ballot(acc);
    int sel = mask ? (__ffsll((unsigned long long)mask) - 1) : 0;
    float w = __shfl(wt, sel, 64);

    uint64_t cbase = (((uint64_t)(row + 1)) << 32) | 0x40000000ull;
    float v[8];
    #pragma unroll
    for (int j = 0; j < 8; j++) v[j] = normal_from(sm64(cbase + (uint64_t)(lane * 8 + j)));
    float d = 0.0f;
    #pragma unroll
    for (int j = 0; j < 8; j++) d += v[j] * mu[j];
    d = wave_sum(d);
    float t2 = 0.0f;
    #pragma unroll
    for (int j = 0; j < 8; j++) { v[j] -= d * mu[j]; t2 += v[j] * v[j]; }
    t2 = wave_sum(t2);
    float ivt = rsqrtf(t2);
    float st = sqrtf(fmaxf(0.0f, 1.0f - w * w)) * ivt;
    float sv[8];
    float s2 = 0.0f;
    #pragma unroll
    for (int j = 0; j < 8; j++) { sv[j] = fmaf(st, v[j], w * mu[j]); s2 += sv[j] * sv[j]; }
    s2 = wave_sum(s2);
    float is = rsqrtf(s2) * 16.0f;
    int2 pk = pack_fp8x8(sv, is);
    *(int2*)(Sb8 + (size_t)row * 512 + pk_off(lane)) = pk;
  }
}

// MFMA GEMM: fp8 e4m3, 256x128 tile, BK=64, 8 iterations, 4 waves, triple-
// buffered DMA staging. EXACT R7/R14 configuration -- the best-measured
// kernel (gemm 52.7us, total 138.3us). Plateau ledger: phases@4w (R3),
// occupancy x1.5/x2 (R2/R4), A-in-reg (R6), redundant-B (R8), merged-
// barrier (R9), memset-offload (R10), 8-phase drain0/counted (R12/R13),
// sampler normal-approx (R15/R16, infra-blocked) -- all refuted/closed.
// m97-class structural plateau at this problem shape (K=512 too shallow
// for the deep-pipelined 256^2 template; 30% MfmaUtil / 4% HBM is the
// shallow-K barrier-bound operating point, not a pipe roofline).
__global__ __launch_bounds__(256, 2) void gemm_lse(const unsigned char* __restrict__ Sb8,
                                                   const unsigned char* __restrict__ Wb8,
                                                   const float4* __restrict__ cparams,
                                                   float* __restrict__ rowsum) {
  __shared__ __align__(16) unsigned char As[3][256 * 64];   // 3 x 16 KB
  __shared__ __align__(16) unsigned char Bs[3][128 * 64];   // 3 x 8 KB
  int tid = threadIdx.x;
  int lane = tid & 63, wave = tid >> 6;
  int tx = lane & 15, tz = lane >> 4;

  int id = blockIdx.x;                       // 64 col-tiles x 20 row-tiles = 1280
  int xcd = id & 7, lid = id >> 3;           // 160 blocks per XCD
  int c0 = (xcd * 8 + (lid & 7)) * 128;      // 8-coltile stripe per XCD
  int r0 = (lid >> 3) * 256;                 // sweep 20 row tiles

  int srow = lane >> 2;                      // 0..15 within chunk
  int slot = lane & 3;
  int kg = slot ^ ((srow >> 1) & 3);         // verified swizzle
  // global pointers: A chunks wave*4..+3 (16 rows each), B chunks wave*2..+1
  const unsigned char* gA[4];
  const unsigned char* gB[2];
  #pragma unroll
  for (int c = 0; c < 4; c++)
    gA[c] = Sb8 + (size_t)(r0 + (wave * 4 + c) * 16 + srow) * 512 + kg * 16;
  #pragma unroll
  for (int c = 0; c < 2; c++)
    gB[c] = Wb8 + (size_t)(c0 + (wave * 2 + c) * 16 + srow) * 512 + kg * 16;
  // wave-uniform LDS chunk bases (DMA adds lane*16)
  int ldsA0 = (wave * 4) * 1024;             // + c*1024
  int ldsB0 = (wave * 2) * 1024;

  f32x4 acc[4][8];
  #pragma unroll
  for (int i = 0; i < 4; i++)
    #pragma unroll
    for (int j = 0; j < 8; j++) acc[i][j] = (f32x4){0.f, 0.f, 0.f, 0.f};

#define STAGE(P, CI)                                         \
  { gld16(gA[0] + (CI) * 64, &As[P][ldsA0]);                 \
    gld16(gA[1] + (CI) * 64, &As[P][ldsA0 + 1024]);          \
    gld16(gA[2] + (CI) * 64, &As[P][ldsA0 + 2048]);          \
    gld16(gA[3] + (CI) * 64, &As[P][ldsA0 + 3072]);          \
    gld16(gB[0] + (CI) * 64, &Bs[P][ldsB0]);                 \
    gld16(gB[1] + (CI) * 64, &Bs[P][ldsB0 + 1024]); }

#define COMPUTE(P)                                                        \
  { l2 af[4];                                                             \
    int sA_ = tz ^ ((tx >> 1) & 3);                                       \
    _Pragma("unroll")                                                     \
    for (int mi = 0; mi < 4; mi++)                                        \
      af[mi] = *(const l2*)&As[P][(wave * 64 + mi * 16 + tx) * 64 + sA_ * 16]; \
    _Pragma("unroll")                                                     \
    for (int h = 0; h < 2; h++) {                                         \
      l2 bf[4];                                                           \
      _Pragma("unroll")                                                   \
      for (int ni = 0; ni < 4; ni++)                                      \
        bf[ni] = *(const l2*)&Bs[P][((h * 4 + ni) * 16 + tx) * 64 + sA_ * 16]; \
      _Pragma("unroll")                                                   \
      for (int mi = 0; mi < 4; mi++)                                      \
        _Pragma("unroll")                                                 \
        for (int ni = 0; ni < 4; ni++)                                    \
          acc[mi][h * 4 + ni] = __builtin_amdgcn_mfma_f32_16x16x32_fp8_fp8(af[mi].x, bf[ni].x, acc[mi][h * 4 + ni], 0, 0, 0); \
      _Pragma("unroll")                                                   \
      for (int mi = 0; mi < 4; mi++)                                      \
        _Pragma("unroll")                                                 \
        for (int ni = 0; ni < 4; ni++)                                    \
          acc[mi][h * 4 + ni] = __builtin_amdgcn_mfma_f32_16x16x32_fp8_fp8(af[mi].y, bf[ni].y, acc[mi][h * 4 + ni], 0, 0, 0); \
    } }

  // prologue: chunks 0,1,2 -> bufs 0,1,2 (18 DMAs); wait chunk 0
  // (12 newer outstanding); barrier.
  STAGE(0, 0);
  STAGE(1, 1);
  STAGE(2, 2);
  asm volatile("s_waitcnt vmcnt(12)" ::: "memory");
  __builtin_amdgcn_s_barrier();

  // iter t: compute buf (t%3); lgkm0+barrier (block done reading the buf);
  // stage chunk t+3 into the SAME buf; gate: chunk t+1 complete while
  // {t+2,t+3}'s DMAs (NGATE) stay in flight; barrier; next iter.
#define GITER(P, IT, NGATE)                                               \
  { COMPUTE(P);                                                           \
    if ((IT) < 7) {                                                       \
      asm volatile("s_waitcnt lgkmcnt(0)\n\ts_barrier" ::: "memory");     \
      if ((IT) + 3 < 8) STAGE(P, (IT) + 3);                               \
      asm volatile("s_waitcnt vmcnt(" #NGATE ")" ::: "memory");           \
      __builtin_amdgcn_s_barrier();                                       \
    } }

  GITER(0, 0, 12) GITER(1, 1, 12) GITER(2, 2, 12)
  GITER(0, 3, 12) GITER(1, 4, 12) GITER(2, 5, 6)
  GITER(0, 6, 0)  GITER(1, 7, 0)

  // epilogue: s += 2^(cubic(acc)) per class (poly pre-scaled for acc=256*cos)
  float4 cp[8];
  #pragma unroll
  for (int ni = 0; ni < 8; ni++) cp[ni] = cparams[c0 + ni * 16 + tx];

  #pragma unroll
  for (int mi = 0; mi < 4; mi++) {
    #pragma unroll
    for (int reg = 0; reg < 4; reg++) {
      float s = 0.0f;
      #pragma unroll
      for (int ni = 0; ni < 8; ni++) {
        float cv = acc[mi][ni][reg];
        float g = fmaf(fmaf(fmaf(cp[ni].w, cv, cp[ni].z), cv, cp[ni].y), cv, cp[ni].x);
        s += exp2f(g);
      }
      #pragma unroll
      for (int o = 1; o < 16; o <<= 1) s += __shfl_xor(s, o, 64);
      if (tx == 0)
        atomicAdd(&rowsum[r0 + wave * 64 + mi * 16 + tz * 4 + reg], s);
    }
  }
}

// finalize: recompute both unit vectors from raw fp32 inputs
__global__ __launch_bounds__(64) void finalize_kernel(const float* __restrict__ params,
                                                      const float* __restrict__ weight,
                                                      const float* __restrict__ rowsum,
                                                      const int* __restrict__ labels,
                                                      const float* __restrict__ lscale,
                                                      float* __restrict__ out) {
  int b = blockIdx.x;
  int lane = threadIdx.x;
  int lab = labels[b];
  const float* pr = params + (size_t)b * (DIMD + 2) + 1;
  const float* wr = weight + (size_t)lab * (DIMD + 2) + 1;
  float nx = 0.0f, nw = 0.0f, d = 0.0f;
  #pragma unroll
  for (int j = 0; j < 8; j++) {
    float xv = pr[j * 64 + lane];
    float wv = wr[j * 64 + lane];
    nx += xv * xv; nw += wv * wv; d += xv * wv;
  }
  nx = wave_sum(nx); nw = wave_sum(nw); d = wave_sum(d);
  if (lane == 0) {
    float k1 = expf(lscale[0]);
    float acc = 0.0f;
    #pragma unroll
    for (int k = 0; k < KSAMP; k++) acc += __logf(rowsum[b * KSAMP + k]);
    float loss = acc * (1.0f / KSAMP) - k1 * d * rsqrtf(nx) * rsqrtf(nw);
    out[(size_t)b * NCLS + lab] = -loss;
  }
}

// ---------------- launch ----------------
extern "C" void kernel_launch(void* const* d_in, const int* in_sizes, int n_in,
                              void* d_out, int out_size, void* d_ws, size_t ws_size,
                              hipStream_t stream) {
  const float* params = (const float*)d_in[0];
  const float* weight = (const float*)d_in[1];
  const float* lscale = (const float*)d_in[2];
  const int*   labels = (const int*)d_in[3];
  float* out = (float*)d_out;
  char* ws = (char*)d_ws;

  unsigned char* muW8    = (unsigned char*)(ws);                    // 8192*512 = 4,194,304
  unsigned char* Sb8     = (unsigned char*)(ws + 4194304);          // 5120*512 = 2,621,440
  float4*        cparams = (float4*)(ws + 6815744);                 // 8192*16  =   131,072
  float*         rowsum  = (float*)(ws + 6946816);                  // 5120*4   =    20,480

  hipLaunchKernelGGL(prep_sample, dim3(2048 + BATCH * KSAMP / 4), dim3(256), 0, stream,
                     weight, params, lscale, muW8, cparams, rowsum, (float4*)out, Sb8);
  hipLaunchKernelGGL(gemm_lse, dim3((NCLS / 128) * (BATCH * KSAMP / 256)), dim3(256), 0, stream,
                     Sb8, muW8, cparams, rowsum);
  hipLaunchKernelGGL(finalize_kernel, dim3(BATCH), dim3(64), 0, stream,
                     params, weight, rowsum, labels, lscale, out);
}